// Round 2
// baseline (553.550 us; speedup 1.0000x reference)
//
#include <hip/hip_runtime.h>

// DIN attention unit, MI355X — round 2: position-per-thread, zero main-loop
// barriers, weights via wave-uniform (scalar) loads from a per-batch blob.
//
// prep : wM[b][j][0..19], c[b][j] = fold(query, W0, b0)   (layer1 algebra:
//        att = [q,k,q-k,q*k] @ W0  ==  c_b + k · M_b)
// pass1: per-position h0_pre -> per-channel sum/sumsq (32ch), j split by wave
// fin0 : mean/var -> scale0/shift0
// pass2: h0_pre -> dice0 -> h1_pre -> sum/sumsq (16ch)   (all in registers)
// fin1 : mean/var -> scale1/shift1
// pass3: full tower -> score -> out[b,:] += score * k
// mask input UNUSED (reference uses unmasked scores — reproduced bug).

#define BB 512
#define TT 2048
#define DD 20
#define C0 32
#define C1 16

#define NTH 256
#define CHUNKS 2
#define TCHUNK (TT / CHUNKS)  // 1024
#define PPT (TCHUNK / NTH)    // 4 positions per thread

// ws float offsets
#define WS_SUM0 0
#define WS_SQ0 32
#define WS_SUM1 64
#define WS_SQ1 80
#define WS_SCALE0 96
#define WS_SHIFT0 128
#define WS_SCALE1 160
#define WS_SHIFT1 176
#define WS_BLOB 192
#define BLOB_J 24             // floats per channel row (20 wM + cj + pad), 96B
#define BLOB_B (C0 * BLOB_J)  // 768 floats per batch

__device__ __forceinline__ float fast_sigmoid(float x) {
    return __builtin_amdgcn_rcpf(1.0f + __expf(-x));
}

__device__ __forceinline__ void load_krow(const float* __restrict__ row,
                                          float* kk) {
    const float4* kr = (const float4*)row;  // rows are 80B => 16B aligned
    float4 a = kr[0], b = kr[1], c = kr[2], d = kr[3], e = kr[4];
    kk[0] = a.x; kk[1] = a.y; kk[2] = a.z; kk[3] = a.w;
    kk[4] = b.x; kk[5] = b.y; kk[6] = b.z; kk[7] = b.w;
    kk[8] = c.x; kk[9] = c.y; kk[10] = c.z; kk[11] = c.w;
    kk[12] = d.x; kk[13] = d.y; kk[14] = d.z; kk[15] = d.w;
    kk[16] = e.x; kk[17] = e.y; kk[18] = e.z; kk[19] = e.w;
}

// ---------------- prep: fold query into layer-1 weights ----------------
__global__ void prep_kernel(const float* __restrict__ query,
                            const float* __restrict__ W0,
                            const float* __restrict__ b0,
                            float* __restrict__ blob) {
    const int b = blockIdx.x * 2 + (threadIdx.x >> 5);
    const int j = threadIdx.x & 31;
    float cj = b0[j];
    float* dst = blob + (size_t)b * BLOB_B + j * BLOB_J;
#pragma unroll
    for (int d = 0; d < DD; ++d) {
        float w_q = W0[d * C0 + j];
        float w_k = W0[(DD + d) * C0 + j];
        float w_d = W0[(2 * DD + d) * C0 + j];
        float w_p = W0[(3 * DD + d) * C0 + j];
        float qd = query[b * DD + d];
        dst[d] = w_k - w_d + qd * w_p;
        cj = fmaf(qd, w_q + w_d, cj);
    }
    dst[20] = cj;
}

// ---------------- pass 1: layer-1 pre-activation stats ----------------
// Channels split across waves (8 each): small accumulator count, cheap
// epilogue. Every wave streams all TCHUNK positions (loads L1-broadcast).
__global__ __launch_bounds__(NTH) void pass1_kernel(
    const float* __restrict__ keys, const float* __restrict__ blob,
    float* __restrict__ sums) {
    const int b = blockIdx.x >> 1, chunk = blockIdx.x & 1;
    const int tid = threadIdx.x, wave = tid >> 6, lane = tid & 63;
    const int j0 = wave * 8;  // wave-uniform channel base
    const float* wb = blob + (size_t)b * BLOB_B;
    const float* kbase = keys + ((size_t)b * TT + chunk * TCHUNK) * DD;

    float s[8], q[8];
#pragma unroll
    for (int v = 0; v < 8; ++v) { s[v] = 0.f; q[v] = 0.f; }

#pragma unroll 1
    for (int it = 0; it < TCHUNK / 64; ++it) {
        float kk[DD];
        load_krow(kbase + (size_t)(it * 64 + lane) * DD, kk);
#pragma unroll
        for (int jj = 0; jj < 8; ++jj) {
            const float* w = wb + (j0 + jj) * BLOB_J;  // wave-uniform
            float h = w[20];
#pragma unroll
            for (int d = 0; d < DD; ++d) h = fmaf(kk[d], w[d], h);
            s[jj] += h;
            q[jj] = fmaf(h, h, q[jj]);
        }
    }
    // wave butterfly per value; lane v keeps value v
    float mine = 0.f;
#pragma unroll
    for (int v = 0; v < 16; ++v) {
        float val = (v < 8) ? s[v] : q[v - 8];
#pragma unroll
        for (int o = 32; o >= 1; o >>= 1) val += __shfl_xor(val, o);
        if (lane == v) mine = val;
    }
    __shared__ float red[64];
    if (lane < 16) {
        int j = j0 + (lane & 7);
        red[(lane < 8 ? 0 : 32) + j] = mine;  // distinct slots per wave
    }
    __syncthreads();
    if (tid < 64) atomicAdd(&sums[WS_SUM0 + tid], red[tid]);
}

// ---------------- finalize: mean/var -> scale/shift ----------------
__global__ void finalize_kernel(float* __restrict__ ws, int nch, int sumOff,
                                int sqOff, int scOff, int shOff) {
    int j = threadIdx.x;
    if (j < nch) {
        const float invN = 1.0f / (float)(BB * TT);
        float mean = ws[sumOff + j] * invN;
        float ex2 = ws[sqOff + j] * invN;
        float var = ex2 - mean * mean;
        float sc = rsqrtf(var + 1e-9f);
        ws[scOff + j] = sc;
        ws[shOff + j] = -mean * sc;
    }
}

// ---------------- pass 2: layer-2 pre-activation stats ----------------
__global__ __launch_bounds__(NTH) void pass2_kernel(
    const float* __restrict__ keys, const float* __restrict__ blob,
    const float* __restrict__ par, const float* __restrict__ a0,
    const float* __restrict__ W1, const float* __restrict__ b1,
    float* __restrict__ sums) {
    const int b = blockIdx.x >> 1, chunk = blockIdx.x & 1;
    const int tid = threadIdx.x, wave = tid >> 6, lane = tid & 63;
    const float* wb = blob + (size_t)b * BLOB_B;
    const float* kbase = keys + ((size_t)b * TT + chunk * TCHUNK) * DD;

    float s1[C1], q1[C1];
#pragma unroll
    for (int v = 0; v < C1; ++v) { s1[v] = 0.f; q1[v] = 0.f; }

#pragma unroll 1
    for (int it = 0; it < PPT; ++it) {
        float kk[DD];
        load_krow(kbase + (size_t)(it * NTH + tid) * DD, kk);
        float h0d[C0];
#pragma unroll
        for (int j = 0; j < C0; ++j) {
            const float* w = wb + j * BLOB_J;  // uniform -> s_load
            float h = w[20];
#pragma unroll
            for (int d = 0; d < DD; ++d) h = fmaf(kk[d], w[d], h);
            float p = fast_sigmoid(fmaf(h, par[WS_SCALE0 + j], par[WS_SHIFT0 + j]));
            float al = a0[j];
            h0d[j] = h * (al + p * (1.0f - al));
        }
        float h1[C1];
#pragma unroll
        for (int jj = 0; jj < C1; ++jj) h1[jj] = b1[jj];
#pragma unroll
        for (int l = 0; l < C0; ++l) {
            const float* wr = W1 + l * C1;  // uniform row -> s_load x16
            float hl = h0d[l];
#pragma unroll
            for (int jj = 0; jj < C1; ++jj) h1[jj] = fmaf(hl, wr[jj], h1[jj]);
        }
#pragma unroll
        for (int jj = 0; jj < C1; ++jj) {
            s1[jj] += h1[jj];
            q1[jj] = fmaf(h1[jj], h1[jj], q1[jj]);
        }
    }
    float mine = 0.f;
#pragma unroll
    for (int v = 0; v < 32; ++v) {
        float val = (v < C1) ? s1[v] : q1[v - C1];
#pragma unroll
        for (int o = 32; o >= 1; o >>= 1) val += __shfl_xor(val, o);
        if (lane == v) mine = val;
    }
    __shared__ float red[4][32];
    if (lane < 32) red[wave][lane] = mine;
    __syncthreads();
    if (tid < 32)
        atomicAdd(&sums[WS_SUM1 + tid],
                  red[0][tid] + red[1][tid] + red[2][tid] + red[3][tid]);
}

// ---------------- pass 3: full tower + weighted key-sum ----------------
__global__ __launch_bounds__(NTH) void pass3_kernel(
    const float* __restrict__ keys, const float* __restrict__ blob,
    const float* __restrict__ par, const float* __restrict__ a0,
    const float* __restrict__ W1, const float* __restrict__ b1,
    const float* __restrict__ a1, const float* __restrict__ wk,
    const float* __restrict__ bk, float* __restrict__ out) {
    const int b = blockIdx.x >> 1, chunk = blockIdx.x & 1;
    const int tid = threadIdx.x, lane = tid & 63;
    const float* wb = blob + (size_t)b * BLOB_B;
    const float* kbase = keys + ((size_t)b * TT + chunk * TCHUNK) * DD;

    float oacc[DD];
#pragma unroll
    for (int d = 0; d < DD; ++d) oacc[d] = 0.f;

#pragma unroll 1
    for (int it = 0; it < PPT; ++it) {
        float kk[DD];
        load_krow(kbase + (size_t)(it * NTH + tid) * DD, kk);
        float h0d[C0];
#pragma unroll
        for (int j = 0; j < C0; ++j) {
            const float* w = wb + j * BLOB_J;
            float h = w[20];
#pragma unroll
            for (int d = 0; d < DD; ++d) h = fmaf(kk[d], w[d], h);
            float p = fast_sigmoid(fmaf(h, par[WS_SCALE0 + j], par[WS_SHIFT0 + j]));
            float al = a0[j];
            h0d[j] = h * (al + p * (1.0f - al));
        }
        float h1[C1];
#pragma unroll
        for (int jj = 0; jj < C1; ++jj) h1[jj] = b1[jj];
#pragma unroll
        for (int l = 0; l < C0; ++l) {
            const float* wr = W1 + l * C1;
            float hl = h0d[l];
#pragma unroll
            for (int jj = 0; jj < C1; ++jj) h1[jj] = fmaf(hl, wr[jj], h1[jj]);
        }
        float score = bk[0];
#pragma unroll
        for (int jj = 0; jj < C1; ++jj) {
            float p = fast_sigmoid(
                fmaf(h1[jj], par[WS_SCALE1 + jj], par[WS_SHIFT1 + jj]));
            float al = a1[jj];
            float hd = h1[jj] * (al + p * (1.0f - al));
            score = fmaf(hd, wk[jj], score);
        }
#pragma unroll
        for (int d = 0; d < DD; ++d) oacc[d] = fmaf(score, kk[d], oacc[d]);
    }
    // wave butterfly per output dim; lane d keeps dim d; one atomic per wave
    float mine = 0.f;
#pragma unroll
    for (int d = 0; d < DD; ++d) {
        float val = oacc[d];
#pragma unroll
        for (int o = 32; o >= 1; o >>= 1) val += __shfl_xor(val, o);
        if (lane == d) mine = val;
    }
    if (lane < DD) atomicAdd(&out[b * DD + lane], mine);
}

extern "C" void kernel_launch(void* const* d_in, const int* in_sizes, int n_in,
                              void* d_out, int out_size, void* d_ws,
                              size_t ws_size, hipStream_t stream) {
    const float* keys = (const float*)d_in[0];
    const float* query = (const float*)d_in[1];
    // d_in[2] = mask: intentionally unused
    const float* W0 = (const float*)d_in[3];
    const float* b0 = (const float*)d_in[4];
    const float* a0 = (const float*)d_in[5];
    const float* W1 = (const float*)d_in[6];
    const float* b1 = (const float*)d_in[7];
    const float* a1 = (const float*)d_in[8];
    const float* wk = (const float*)d_in[9];
    const float* bk = (const float*)d_in[10];
    float* out = (float*)d_out;
    float* ws = (float*)d_ws;
    float* blob = ws + WS_BLOB;  // 512*768 floats = 1.5 MB of scratch

    hipMemsetAsync(ws, 0, 96 * sizeof(float), stream);  // sums area
    hipMemsetAsync(out, 0, (size_t)out_size * sizeof(float), stream);

    prep_kernel<<<BB / 2, 64, 0, stream>>>(query, W0, b0, blob);

    dim3 grid(BB * CHUNKS), blk(NTH);
    pass1_kernel<<<grid, blk, 0, stream>>>(keys, blob, ws);
    finalize_kernel<<<1, 32, 0, stream>>>(ws, 32, WS_SUM0, WS_SQ0, WS_SCALE0,
                                          WS_SHIFT0);
    pass2_kernel<<<grid, blk, 0, stream>>>(keys, blob, ws, a0, W1, b1, ws);
    finalize_kernel<<<1, 16, 0, stream>>>(ws, 16, WS_SUM1, WS_SQ1, WS_SCALE1,
                                          WS_SHIFT1);
    pass3_kernel<<<grid, blk, 0, stream>>>(keys, blob, ws, a0, W1, b1, a1, wk,
                                           bk, out);
}